// Round 10
// baseline (238.363 us; speedup 1.0000x reference)
//
#include <hip/hip_runtime.h>

#define B 128
#define S 200
#define LW 50
#define Q 20
#define V 50000
#define VH 25000
#define D 128
#define NH 3
#define VD (V * D)              // 6,400,000
#define BSD (B * S * D)        // 3,276,800
#define BS (B * S)             // 25,600

typedef __bf16 bf16x8 __attribute__((ext_vector_type(8)));
typedef float f32x4 __attribute__((ext_vector_type(4)));
typedef float f32x2 __attribute__((ext_vector_type(2)));
typedef unsigned int u32x4 __attribute__((ext_vector_type(4)));

// ---- bf16 helpers (bit-level, RNE pack) -----------------------------------
__device__ __forceinline__ unsigned int f2bf_rne(float f) {
  union { float f; unsigned int u; } c; c.f = f;
  return (c.u + 0x7FFFu + ((c.u >> 16) & 1u)) >> 16;
}
__device__ __forceinline__ unsigned int pack2(float a, float b) {
  return f2bf_rne(a) | (f2bf_rne(b) << 16);
}
__device__ __forceinline__ float bf_lo(unsigned int q) {
  union { unsigned int u; float f; } c; c.u = q << 16; return c.f;
}
__device__ __forceinline__ float bf_hi(unsigned int q) {
  union { unsigned int u; float f; } c; c.u = q & 0xFFFF0000u; return c.f;
}

// ---------------------------------------------------------------------------
// Compaction: per sentence, split the 50 words into two vocab-half lists.
// Entry = idx | (j << 16). Rows padded to 50 with in-half sentinel idx
// (weights are masked by cnt in the gather, so only the address must be safe).
// ---------------------------------------------------------------------------
__global__ __launch_bounds__(256) void k_compact(
    const int* __restrict__ story, unsigned int* __restrict__ CS,
    int* __restrict__ cnts) {
  int sent = blockIdx.x * 256 + threadIdx.x;   // 25600 threads
  const int* w = story + sent * LW;
  unsigned int* row0 = CS + ((size_t)0 * BS + sent) * LW;
  unsigned int* row1 = CS + ((size_t)1 * BS + sent) * LW;
  int c0 = 0, c1 = 0;
  for (int j = 0; j < LW; ++j) {
    unsigned int idx = (unsigned int)w[j];
    unsigned int e = idx | ((unsigned int)j << 16);
    if (idx < (unsigned int)VH) row0[c0++] = e;
    else row1[c1++] = e;
  }
  for (int s = c0; s < LW; ++s) row0[s] = 0u;
  for (int s = c1; s < LW; ++s) row1[s] = (unsigned int)VH;
  cnts[0 * BS + sent] = c0;
  cnts[1 * BS + sent] = c1;
}

// ---------------------------------------------------------------------------
// Repack 2 tables {kbase, kbase+1} -> wide-row bf16 layout ESMW (in-place
// per phase; 25.6 MB total):
//   region r = ((t*2 + dh)*2 + h), t = k-kbase, dh = d-half, h = vocab-half
//   ESMW[(r*VH + v') * 32 + cc]  (uint cc=0..31 covers d = dh*64 + 2cc,+1)
// Region = 25000 x 128 B = 3.2 MB -> one XCD's L2. A word's (t,dh) data is
// ONE 128-B contiguous request (vs 64 B before) -> halves L2 request count.
// ---------------------------------------------------------------------------
__global__ __launch_bounds__(256) void k_repack_w(
    const float* __restrict__ embs, unsigned int* __restrict__ ESMW,
    int kbase) {
  int v = blockIdx.x * 4 + (threadIdx.x >> 6);
  int l = threadIdx.x & 63;
  int dh = l >> 5, cc = l & 31;
  int h = (v >= VH) ? 1 : 0;
  int vp = v - h * VH;
#pragma unroll
  for (int t = 0; t < 2; ++t) {
    int k = kbase + t;
    f32x2 e = __builtin_nontemporal_load(
        (const f32x2*)(embs + (size_t)k * VD + (size_t)v * D + 2 * l));
    int r = (t * 2 + dh) * 2 + h;
    __builtin_nontemporal_store(
        pack2(e.x, e.y), ESMW + ((size_t)r * VH + vp) * 32 + cc);
  }
}

// ---------------------------------------------------------------------------
// TA/TC -> bf16 packed pairs, LINEAR d order: Tp[row*64+u] = (d=2u, 2u+1).
// ---------------------------------------------------------------------------
__global__ __launch_bounds__(256) void k_packT(
    const float* __restrict__ TA, const float* __restrict__ TC,
    unsigned int* __restrict__ TAp, unsigned int* __restrict__ TCp) {
  int idx = blockIdx.x * 256 + threadIdx.x;   // 0 .. NH*S*64-1
  int row = idx >> 6;
  int u = idx & 63;
  const float2 a = *(const float2*)(TA + (size_t)row * D + 2 * u);
  const float2 c = *(const float2*)(TC + (size_t)row * D + 2 * u);
  TAp[idx] = pack2(a.x, a.y);
  TCp[idx] = pack2(c.x, c.y);
}

// ---------------------------------------------------------------------------
// Vocab-half-split gather, phase p = tables {2p, 2p+1}.
// Block bi: unit r = bi&7 -> (t,dh,h); round-robin dispatch pins unit r to
// XCD r, whose L2 holds only that 3.2 MB region. 32 sentences per block
// (4 waves x 8); 8 lanes per sentence read one 128-B row per list entry.
// Output: per-half partial Pp[(ktab*2+h)][sent][64 uints, linear d pairs]
// (bf16; halves combined in k_hops). Loop runs to the wave-max count with
// masked coefficients for the padded tail.
// ---------------------------------------------------------------------------
__global__ __launch_bounds__(256) void k_gather_h(
    const unsigned int* __restrict__ CS, const int* __restrict__ cnts,
    const u32x4* __restrict__ ESMW4, unsigned int* __restrict__ Pp,
    int phase) {
  __shared__ unsigned int sent_ent[32 * LW];   // 6400 B
  __shared__ int scnt[32];
  int r = blockIdx.x & 7;
  int h = r & 1;
  int dh = (r >> 1) & 1;
  int t = r >> 2;
  int ktab = 2 * phase + t;
  int s0 = (blockIdx.x >> 3) * 32;
  int tid = threadIdx.x;
  const unsigned int* src = CS + ((size_t)h * BS + s0) * LW;
  for (int e = tid; e < 32 * LW; e += 256)
    sent_ent[e] = __builtin_nontemporal_load(src + e);
  if (tid < 32) scnt[tid] = cnts[h * BS + s0 + tid];
  __syncthreads();

  int w = tid >> 6, l = tid & 63;
  int ss = l >> 3, q8 = l & 7;
  int sl = w * 8 + ss;                  // sentence slot in block
  int cnt = scnt[sl];
  int wmax = cnt;
  wmax = max(wmax, __shfl_xor(wmax, 8));
  wmax = max(wmax, __shfl_xor(wmax, 16));
  wmax = max(wmax, __shfl_xor(wmax, 32));
  const u32x4* reg = ESMW4 + (size_t)r * VH * 8;
  const unsigned int* ent = sent_ent + sl * LW;
  float SA[8] = {0.f, 0.f, 0.f, 0.f, 0.f, 0.f, 0.f, 0.f};
  float SB[8] = {0.f, 0.f, 0.f, 0.f, 0.f, 0.f, 0.f, 0.f};
  unsigned int hoff = (unsigned int)(h * VH);
  for (int j = 0; j < wmax; j += 2) {
    unsigned int e0 = ent[j];
    unsigned int e1 = ent[j + 1];      // always within the padded 50 slots
    unsigned int vp0 = (e0 & 0xFFFFu) - hoff;
    unsigned int vp1 = (e1 & 0xFFFFu) - hoff;
    u32x4 q0 = reg[(size_t)vp0 * 8 + q8];
    u32x4 q1 = reg[(size_t)vp1 * 8 + q8];
    float jj0 = (float)((e0 >> 16) + 1) * (1.0f / LW);
    float jj1 = (float)((e1 >> 16) + 1) * (1.0f / LW);
    bool a0 = (j < cnt), a1 = (j + 1 < cnt);
    float al0 = a0 ? (1.0f - jj0) : 0.f;
    float bl0 = a0 ? (2.0f * jj0 - 1.0f) : 0.f;
    float al1 = a1 ? (1.0f - jj1) : 0.f;
    float bl1 = a1 ? (2.0f * jj1 - 1.0f) : 0.f;
    float e0f[8], e1f[8];
    e0f[0] = bf_lo(q0.x); e0f[1] = bf_hi(q0.x);
    e0f[2] = bf_lo(q0.y); e0f[3] = bf_hi(q0.y);
    e0f[4] = bf_lo(q0.z); e0f[5] = bf_hi(q0.z);
    e0f[6] = bf_lo(q0.w); e0f[7] = bf_hi(q0.w);
    e1f[0] = bf_lo(q1.x); e1f[1] = bf_hi(q1.x);
    e1f[2] = bf_lo(q1.y); e1f[3] = bf_hi(q1.y);
    e1f[4] = bf_lo(q1.z); e1f[5] = bf_hi(q1.z);
    e1f[6] = bf_lo(q1.w); e1f[7] = bf_hi(q1.w);
#pragma unroll
    for (int i = 0; i < 8; ++i) {
      SA[i] += e0f[i] * al0 + e1f[i] * al1;
      SB[i] += e0f[i] * bl0 + e1f[i] * bl1;
    }
  }
  int dbase = dh * 64 + q8 * 8;
  float kd[8];
#pragma unroll
  for (int i = 0; i < 8; ++i) kd[i] = (float)(dbase + i + 1) * (1.0f / D);
  int sent = s0 + sl;
  u32x4 og;
  og.x = pack2(SA[0] + kd[0] * SB[0], SA[1] + kd[1] * SB[1]);
  og.y = pack2(SA[2] + kd[2] * SB[2], SA[3] + kd[3] * SB[3]);
  og.z = pack2(SA[4] + kd[4] * SB[4], SA[5] + kd[5] * SB[5]);
  og.w = pack2(SA[6] + kd[6] * SB[6], SA[7] + kd[7] * SB[7]);
  __builtin_nontemporal_store(
      og, (u32x4*)Pp + (((size_t)(ktab * 2 + h) * BS + sent) * 16 + dh * 8 + q8));
}

// ---------------------------------------------------------------------------
// Fused: query gather (f32 embs[0]) -> 3 hops over per-half partials
// (G = P0 + P1, linear d) + bf16 TAp/TCp -> u packed bf16.
// One block per b, 1024 threads.
// ---------------------------------------------------------------------------
__global__ __launch_bounds__(1024) void k_hops(
    const unsigned int* __restrict__ P, const unsigned int* __restrict__ TAp,
    const unsigned int* __restrict__ TCp, const int* __restrict__ query,
    const float* __restrict__ emb0, unsigned int* __restrict__ ubf) {
  __shared__ float su[D];
  __shared__ float sp[S];
  __shared__ float sred[2];
  __shared__ float4 oacc[32][32];
  int b = blockIdx.x;
  int t = threadIdx.x;
  if (t < D) {
    float kd = (float)(t + 1) * (1.0f / D);
    float acc = 0.f;
    for (int q = 0; q < Q; ++q) {
      int idx = query[b * Q + q];
      float jj = (float)(q + 1) * (1.0f / Q);
      float pe = 1.0f - jj - kd * (1.0f - 2.0f * jj);
      acc += emb0[(size_t)idx * D + t] * pe;
    }
    su[t] = acc;
  }
  __syncthreads();
  for (int hop = 0; hop < NH; ++hop) {
    const unsigned int* m0 = P + ((size_t)(hop * 2 + 0) * BS + (size_t)b * S) * 64;
    const unsigned int* m1 = P + ((size_t)(hop * 2 + 1) * BS + (size_t)b * S) * 64;
    const unsigned int* c0 = P + ((size_t)((hop + 1) * 2 + 0) * BS + (size_t)b * S) * 64;
    const unsigned int* c1 = P + ((size_t)((hop + 1) * 2 + 1) * BS + (size_t)b * S) * 64;
    const unsigned int* ta = TAp + (size_t)hop * S * 64;
    const unsigned int* tc = TCp + (size_t)hop * S * 64;
    if (t < 4 * S) {
      int sl = t >> 2, p = t & 3;
      size_t off = (size_t)sl * 64 + p * 16;
      const uint2* g0 = (const uint2*)(m0 + off);
      const uint2* g1 = (const uint2*)(m1 + off);
      const uint2* tr = (const uint2*)(ta + off);
      float sc = 0.f;
#pragma unroll
      for (int i = 0; i < 8; ++i) {
        uint2 a2 = g0[i];
        uint2 b2 = g1[i];
        uint2 t2 = tr[i];
        int dd = p * 32 + 4 * i;
        sc += (bf_lo(a2.x) + bf_lo(b2.x) + bf_lo(t2.x)) * su[dd + 0];
        sc += (bf_hi(a2.x) + bf_hi(b2.x) + bf_hi(t2.x)) * su[dd + 1];
        sc += (bf_lo(a2.y) + bf_lo(b2.y) + bf_lo(t2.y)) * su[dd + 2];
        sc += (bf_hi(a2.y) + bf_hi(b2.y) + bf_hi(t2.y)) * su[dd + 3];
      }
      sc += __shfl_xor(sc, 1);
      sc += __shfl_xor(sc, 2);
      if (p == 0) sp[sl] = sc;
    }
    __syncthreads();
    if (t < 64) {
      float mx = -1e30f;
      for (int s = t; s < S; s += 64) mx = fmaxf(mx, sp[s]);
#pragma unroll
      for (int off = 1; off < 64; off <<= 1) mx = fmaxf(mx, __shfl_xor(mx, off));
      float sum = 0.f;
      for (int s = t; s < S; s += 64) sum += expf(sp[s] - mx);
#pragma unroll
      for (int off = 1; off < 64; off <<= 1) sum += __shfl_xor(sum, off);
      if (t == 0) { sred[0] = mx; sred[1] = sum; }
    }
    __syncthreads();
    float mx = sred[0];
    float inv = 1.0f / sred[1];
    if (t < S) sp[t] = expf(sp[t] - mx) * inv;
    __syncthreads();
    {
      int g = t >> 5, c = t & 31;
      float4 o4 = {0.f, 0.f, 0.f, 0.f};
      for (int s = g; s < S; s += 32) {
        float p5 = sp[s];
        uint2 a2 = *(const uint2*)(c0 + (size_t)s * 64 + 2 * c);
        uint2 b2 = *(const uint2*)(c1 + (size_t)s * 64 + 2 * c);
        uint2 t2 = *(const uint2*)(tc + (size_t)s * 64 + 2 * c);
        o4.x += p5 * (bf_lo(a2.x) + bf_lo(b2.x) + bf_lo(t2.x));
        o4.y += p5 * (bf_hi(a2.x) + bf_hi(b2.x) + bf_hi(t2.x));
        o4.z += p5 * (bf_lo(a2.y) + bf_lo(b2.y) + bf_lo(t2.y));
        o4.w += p5 * (bf_hi(a2.y) + bf_hi(b2.y) + bf_hi(t2.y));
      }
      oacc[g][c] = o4;
    }
    __syncthreads();
    if (t < 32) {
      int d0 = 4 * t;
      float4 o = oacc[0][t];
#pragma unroll
      for (int g = 1; g < 32; ++g) {
        float4 x = oacc[g][t];
        o.x += x.x; o.y += x.y; o.z += x.z; o.w += x.w;
      }
      su[d0 + 0] += o.x;
      su[d0 + 1] += o.y;
      su[d0 + 2] += o.z;
      su[d0 + 3] += o.w;
    }
    __syncthreads();
  }
  if (t < 64) ubf[b * 64 + t] = pack2(su[2 * t], su[2 * t + 1]);
}

// ---------------------------------------------------------------------------
// logits via mfma_f32_16x16x32_bf16. B-frag from ESMW phase-1 layout
// (t=1 -> table 3): region 4 + 2*(kk>>1) + h, uint4 idx (kk&1)*4 + lk.
// Batch split over blockIdx.y (4 m-tiles each).
// ---------------------------------------------------------------------------
__global__ __launch_bounds__(256) void k_logits_mfma(
    const uint4* __restrict__ ubf,    // [B][16] uint4 (row-major d)
    const u32x4* __restrict__ esmw4,  // wide-row layout, uint4 granularity
    float* __restrict__ out) {
  int wid = threadIdx.x >> 6;
  int l = threadIdx.x & 63;
  int lr = l & 15;
  int lk = l >> 4;
  int vbase = blockIdx.x * 128 + wid * 32;
  int mbase = blockIdx.y * 4;
  u32x4 bfrag[2][4];
#pragma unroll
  for (int vs = 0; vs < 2; ++vs) {
    int v = vbase + vs * 16 + lr;
    if (v >= V) v = V - 1;  // clamp loads; stores guarded
    int h = (v >= VH) ? 1 : 0;
    int vp = v - h * VH;
#pragma unroll
    for (int kk = 0; kk < 4; ++kk)
      bfrag[vs][kk] =
          esmw4[((size_t)(4 + 2 * (kk >> 1) + h) * VH + vp) * 8 +
                (kk & 1) * 4 + lk];
  }
  f32x4 acc[2][4];
#pragma unroll
  for (int vs = 0; vs < 2; ++vs)
#pragma unroll
    for (int m = 0; m < 4; ++m) {
      f32x4 z = {0.f, 0.f, 0.f, 0.f};
      acc[vs][m] = z;
    }
#pragma unroll
  for (int m = 0; m < 4; ++m) {
    int gm = mbase + m;
    uint4 afrag[4];
#pragma unroll
    for (int kk = 0; kk < 4; ++kk)
      afrag[kk] = ubf[(gm * 16 + lr) * 16 + kk * 4 + lk];
#pragma unroll
    for (int vs = 0; vs < 2; ++vs)
#pragma unroll
      for (int kk = 0; kk < 4; ++kk)
        acc[vs][m] = __builtin_amdgcn_mfma_f32_16x16x32_bf16(
            __builtin_bit_cast(bf16x8, afrag[kk]),
            __builtin_bit_cast(bf16x8, bfrag[vs][kk]), acc[vs][m], 0, 0, 0);
  }
#pragma unroll
  for (int vs = 0; vs < 2; ++vs) {
    int v = vbase + vs * 16 + lr;
    if (v < V) {
#pragma unroll
      for (int m = 0; m < 4; ++m)
#pragma unroll
        for (int r = 0; r < 4; ++r)
          out[(size_t)((mbase + m) * 16 + lk * 4 + r) * V + v] = acc[vs][m][r];
    }
  }
}

// ---------------------------------------------------------------------------
// Round-1 f32 fallback kernels (used only if ws too small)
// ---------------------------------------------------------------------------
__global__ __launch_bounds__(128) void k_gather_query(
    const int* __restrict__ query, const float* __restrict__ embs,
    float* __restrict__ u) {
  int b = blockIdx.x;
  int d = threadIdx.x;
  float kd = (float)(d + 1) / (float)D;
  float acc = 0.f;
  for (int q = 0; q < Q; ++q) {
    int idx = query[b * Q + q];
    float jj = (float)(q + 1) / (float)Q;
    float pe = 1.0f - jj - kd * (1.0f - 2.0f * jj);
    acc += embs[(size_t)idx * D + d] * pe;
  }
  u[b * D + d] = acc;
}

__global__ __launch_bounds__(128) void k_gather_story(
    const int* __restrict__ story, const float* __restrict__ embs,
    float* __restrict__ G) {
  int bs = blockIdx.x;
  int d = threadIdx.x;
  const int* w = story + bs * LW;
  float kd = (float)(d + 1) / (float)D;
  float a0 = 0.f, a1 = 0.f, a2 = 0.f, a3 = 0.f;
  for (int l = 0; l < LW; ++l) {
    int idx = w[l];
    float jj = (float)(l + 1) / (float)LW;
    float pe = 1.0f - jj - kd * (1.0f - 2.0f * jj);
    size_t base = (size_t)idx * D + d;
    a0 += embs[base] * pe;
    a1 += embs[base + (size_t)VD] * pe;
    a2 += embs[base + (size_t)(2 * VD)] * pe;
    a3 += embs[base + (size_t)(3 * VD)] * pe;
  }
  size_t o = (size_t)bs * D + d;
  G[o] = a0;
  G[o + (size_t)BSD] = a1;
  G[o + (size_t)(2 * BSD)] = a2;
  G[o + (size_t)(3 * BSD)] = a3;
}

__global__ __launch_bounds__(256) void k_hops_f32(
    const float* __restrict__ G, const float* __restrict__ TA,
    const float* __restrict__ TC, float* __restrict__ u) {
  __shared__ float su[D];
  __shared__ float sp[S];
  __shared__ float sred[2];
  int b = blockIdx.x;
  int t = threadIdx.x;
  if (t < D) su[t] = u[b * D + t];
  __syncthreads();
  for (int hop = 0; hop < NH; ++hop) {
    const float* Gm = G + (size_t)hop * BSD + (size_t)b * S * D;
    const float* Gc = G + (size_t)(hop + 1) * BSD + (size_t)b * S * D;
    const float* ta = TA + hop * S * D;
    const float* tc = TC + hop * S * D;
    if (t < S) {
      float sc = 0.f;
      for (int d = 0; d < D; ++d) sc += (Gm[t * D + d] + ta[t * D + d]) * su[d];
      sp[t] = sc;
    }
    __syncthreads();
    if (t < 64) {
      float mx = -1e30f;
      for (int s = t; s < S; s += 64) mx = fmaxf(mx, sp[s]);
#pragma unroll
      for (int off = 1; off < 64; off <<= 1) mx = fmaxf(mx, __shfl_xor(mx, off));
      float sum = 0.f;
      for (int s = t; s < S; s += 64) sum += expf(sp[s] - mx);
#pragma unroll
      for (int off = 1; off < 64; off <<= 1) sum += __shfl_xor(sum, off);
      if (t == 0) { sred[0] = mx; sred[1] = sum; }
    }
    __syncthreads();
    float mx = sred[0];
    float inv = 1.0f / sred[1];
    if (t < S) sp[t] = expf(sp[t] - mx) * inv;
    __syncthreads();
    if (t < D) {
      float o = 0.f;
      for (int s = 0; s < S; ++s) o += sp[s] * (Gc[s * D + t] + tc[s * D + t]);
      su[t] += o;
    }
    __syncthreads();
  }
  if (t < D) u[b * D + t] = su[t];
}

__global__ __launch_bounds__(256) void k_logits_f32(
    const float* __restrict__ u, const float* __restrict__ e3,
    float* __restrict__ out) {
  __shared__ float sE[64][129];
  __shared__ float sU[64][129];
  int v0 = blockIdx.x * 64;
  int b0 = blockIdx.y * 64;
  int t = threadIdx.x;
  for (int i = 0; i < 32; ++i) {
    int lin = i * 256 + t;
    int r = lin >> 7, c = lin & 127;
    int v = v0 + r;
    sE[r][c] = (v < V) ? e3[(size_t)v * D + c] : 0.f;
    sU[r][c] = u[(b0 + r) * D + c];
  }
  __syncthreads();
  int tv = (t & 15) * 4;
  int tb = (t >> 4) * 4;
  float acc[4][4] = {};
  for (int d = 0; d < D; ++d) {
    float ev[4], ub[4];
#pragma unroll
    for (int i = 0; i < 4; ++i) ev[i] = sE[tv + i][d];
#pragma unroll
    for (int j = 0; j < 4; ++j) ub[j] = sU[tb + j][d];
#pragma unroll
    for (int j = 0; j < 4; ++j)
#pragma unroll
      for (int i = 0; i < 4; ++i) acc[j][i] += ub[j] * ev[i];
  }
  for (int j = 0; j < 4; ++j)
    for (int i = 0; i < 4; ++i) {
      int v = v0 + tv + i;
      if (v < V) out[(size_t)(b0 + tb + j) * V + v] = acc[j][i];
    }
}

extern "C" void kernel_launch(void* const* d_in, const int* in_sizes, int n_in,
                              void* d_out, int out_size, void* d_ws,
                              size_t ws_size, hipStream_t stream) {
  (void)in_sizes; (void)n_in; (void)out_size;
  const int* story = (const int*)d_in[0];
  const int* query = (const int*)d_in[1];
  const float* embs = (const float*)d_in[2];
  const float* TA = (const float*)d_in[3];
  const float* TC = (const float*)d_in[4];
  float* out = (float*)d_out;

  const size_t esmw_bytes = (size_t)8 * VH * 128;        // 25.6 MB
  const size_t pp_bytes = (size_t)8 * BS * 64 * 4;       // 52.4 MB
  const size_t cs_bytes = (size_t)2 * BS * LW * 4;       // 10.24 MB
  const size_t cnt_bytes = (size_t)2 * BS * 4;           // 204.8 KB
  const size_t tp_bytes = (size_t)NH * S * 64 * 4;       // 153.6 KB each
  const size_t ub_bytes = (size_t)B * 64 * 4;            // 32 KB
  const size_t need = esmw_bytes + pp_bytes + cs_bytes + cnt_bytes +
                      2 * tp_bytes + ub_bytes;           // ~88.8 MB

  if (ws_size >= need) {
    char* p = (char*)d_ws;
    unsigned int* ESMW = (unsigned int*)p;   p += esmw_bytes;
    unsigned int* Pp = (unsigned int*)p;     p += pp_bytes;
    unsigned int* CS = (unsigned int*)p;     p += cs_bytes;
    int* cnts = (int*)p;                     p += cnt_bytes;
    unsigned int* TAp = (unsigned int*)p;    p += tp_bytes;
    unsigned int* TCp = (unsigned int*)p;    p += tp_bytes;
    unsigned int* ubf = (unsigned int*)p;

    k_compact<<<BS / 256, 256, 0, stream>>>(story, CS, cnts);
    k_packT<<<NH * S * 64 / 256, 256, 0, stream>>>(TA, TC, TAp, TCp);
    k_repack_w<<<V / 4, 256, 0, stream>>>(embs, ESMW, 0);
    k_gather_h<<<6400, 256, 0, stream>>>(
        CS, cnts, (const u32x4*)ESMW, Pp, 0);
    k_repack_w<<<V / 4, 256, 0, stream>>>(embs, ESMW, 2);  // in-place
    k_gather_h<<<6400, 256, 0, stream>>>(
        CS, cnts, (const u32x4*)ESMW, Pp, 1);
    k_hops<<<B, 1024, 0, stream>>>(Pp, TAp, TCp, query, embs, ubf);
    k_logits_mfma<<<dim3((V + 127) / 128, 2), 256, 0, stream>>>(
        (const uint4*)ubf, (const u32x4*)ESMW, out);
  } else {
    float* G = (float*)d_ws;
    float* u = G + 4 * (size_t)BSD;
    k_gather_query<<<B, D, 0, stream>>>(query, embs, u);
    k_gather_story<<<B * S, D, 0, stream>>>(story, embs, G);
    k_hops_f32<<<B, 256, 0, stream>>>(G, TA, TC, u);
    k_logits_f32<<<dim3((V + 63) / 64, B / 64), 256, 0, stream>>>(
        u, embs + 3 * (size_t)VD, out);
  }
}